// Round 1
// baseline (94487.335 us; speedup 1.0000x reference)
//
#include <hip/hip_runtime.h>

#define HIDDEN   2048
#define T_STEPS  8192
#define WASHOUT  200
#define NWG      256
#define NTHR     256
#define COLS     32          // columns per lane (2048 / 64)
#define BAR_UINTS (18 * 32)  // 16 leaf counters + root + gen, 128B apart

// ws layout:
//   [0)                 float xbuf[2][HIDDEN]   (double-buffered state)
//   [2*HIDDEN*4)        unsigned bar[BAR_UINTS] (barrier counters)

__global__ void esn_init(unsigned* __restrict__ bar) {
  if (threadIdx.x < BAR_UINTS) bar[threadIdx.x] = 0u;
}

__global__ __launch_bounds__(NTHR, 1) void esn_main(
    const float* __restrict__ u,
    const float* __restrict__ w_in,
    const float* __restrict__ w_res,
    const float* __restrict__ w_out,
    float* __restrict__ out,
    float* __restrict__ xbuf,
    unsigned* __restrict__ bar)
{
  const int g  = blockIdx.x;   // 0..255, one WG per CU
  const int j  = threadIdx.x;  // 0..255
  const int wv = j >> 6;       // wave 0..3
  const int l  = j & 63;       // lane

  __shared__ float x_s[HIDDEN];
  __shared__ float red[4];

  // each wave owns 2 rows of W_res; each lane 32 columns (stride 64)
  const int r0 = g * 8 + 2 * wv;
  const int r1 = r0 + 1;

  float wr0[COLS], wr1[COLS];
#pragma unroll
  for (int m = 0; m < COLS; ++m) {
    wr0[m] = w_res[r0 * HIDDEN + l + 64 * m];
    wr1[m] = w_res[r1 * HIDDEN + l + 64 * m];
  }
  const float win0 = w_in[r0];
  const float win1 = w_in[r1];
  float wo[8];
#pragma unroll
  for (int k = 0; k < 8; ++k) wo[k] = w_out[j + 256 * k];

  unsigned* leafc = bar + (g >> 4) * 32;
  unsigned* rootc = bar + 16 * 32;
  unsigned* genp  = bar + 17 * 32;

  for (int t = 0; t < T_STEPS; ++t) {
    float d0 = 0.f, d1 = 0.f;
    if (t > 0) {
      // stage x_{t-1} into LDS (agent-scope loads: L2-bypassing, always fresh)
      float* xb = xbuf + ((t - 1) & 1) * HIDDEN;
#pragma unroll
      for (int k = 0; k < 8; ++k) {
        int idx = j + 256 * k;
        x_s[idx] = __hip_atomic_load(xb + idx, __ATOMIC_RELAXED,
                                     __HIP_MEMORY_SCOPE_AGENT);
      }
      __syncthreads();
#pragma unroll
      for (int m = 0; m < COLS; ++m) {
        float xv = x_s[l + 64 * m];
        d0 = fmaf(wr0[m], xv, d0);
        d1 = fmaf(wr1[m], xv, d1);
      }
    }
    // wave-local reduction (row fully within one wave)
#pragma unroll
    for (int off = 32; off >= 1; off >>= 1) {
      d0 += __shfl_down(d0, off, 64);
      d1 += __shfl_down(d1, off, 64);
    }
    const float ut = u[t];
    if (l == 0) {
      float x0 = tanhf(fmaf(win0, ut, d0));
      float x1 = tanhf(fmaf(win1, ut, d1));
      float* xw = xbuf + (t & 1) * HIDDEN;
      __hip_atomic_store(xw + r0, x0, __ATOMIC_RELAXED, __HIP_MEMORY_SCOPE_AGENT);
      __hip_atomic_store(xw + r1, x1, __ATOMIC_RELAXED, __HIP_MEMORY_SCOPE_AGENT);
    }
    // drain all 4 waves' publish stores (per-wave vmcnt(0) before s_barrier)
    __syncthreads();

    const unsigned target = (unsigned)(t + 1);
    // arrive (release RMW chain: leaf -> root -> gen)
    if (j == 0) {
      unsigned o = __hip_atomic_fetch_add(leafc, 1u, __ATOMIC_RELEASE,
                                          __HIP_MEMORY_SCOPE_AGENT);
      if (o == 16u * target - 1u) {
        unsigned ro = __hip_atomic_fetch_add(rootc, 1u, __ATOMIC_RELEASE,
                                             __HIP_MEMORY_SCOPE_AGENT);
        if (ro == 16u * target - 1u) {
          __hip_atomic_store(genp, target, __ATOMIC_RELEASE,
                             __HIP_MEMORY_SCOPE_AGENT);
        }
      }
    }

    // readout dot for x_{t-1}, hidden under barrier latency; rotating WG
    if (t >= WASHOUT + 1 && g == (t & 255)) {
      float p = 0.f;
#pragma unroll
      for (int k = 0; k < 8; ++k) p = fmaf(x_s[j + 256 * k], wo[k], p);
#pragma unroll
      for (int off = 32; off >= 1; off >>= 1) p += __shfl_down(p, off, 64);
      if (l == 0) red[wv] = p;
      __syncthreads();
      if (j == 0) out[t - 1 - WASHOUT] = red[0] + red[1] + red[2] + red[3];
    }

    // wait
    if (j == 0) {
      while (__hip_atomic_load(genp, __ATOMIC_ACQUIRE,
                               __HIP_MEMORY_SCOPE_AGENT) < target) {
        __builtin_amdgcn_s_sleep(2);
      }
    }
    __syncthreads();
  }

  // epilogue: readout for x_{T-1}
  if (g == 0) {
    float* xb = xbuf + ((T_STEPS - 1) & 1) * HIDDEN;
#pragma unroll
    for (int k = 0; k < 8; ++k) {
      int idx = j + 256 * k;
      x_s[idx] = __hip_atomic_load(xb + idx, __ATOMIC_RELAXED,
                                   __HIP_MEMORY_SCOPE_AGENT);
    }
    __syncthreads();
    float p = 0.f;
#pragma unroll
    for (int k = 0; k < 8; ++k) p = fmaf(x_s[j + 256 * k], wo[k], p);
#pragma unroll
    for (int off = 32; off >= 1; off >>= 1) p += __shfl_down(p, off, 64);
    if (l == 0) red[wv] = p;
    __syncthreads();
    if (j == 0) out[T_STEPS - 1 - WASHOUT] = red[0] + red[1] + red[2] + red[3];
  }
}

extern "C" void kernel_launch(void* const* d_in, const int* in_sizes, int n_in,
                              void* d_out, int out_size, void* d_ws, size_t ws_size,
                              hipStream_t stream) {
  const float* u     = (const float*)d_in[0];
  const float* w_in  = (const float*)d_in[1];
  const float* w_res = (const float*)d_in[2];
  const float* w_out = (const float*)d_in[3];
  float* out   = (float*)d_out;
  float* xbuf  = (float*)d_ws;
  unsigned* bar = (unsigned*)((char*)d_ws + 2 * HIDDEN * sizeof(float));

  esn_init<<<1, BAR_UINTS, 0, stream>>>(bar);
  esn_main<<<NWG, NTHR, 0, stream>>>(u, w_in, w_res, w_out, out, xbuf, bar);
}

// Round 2
// 53235.571 us; speedup vs baseline: 1.7749x; 1.7749x over previous
//
#include <hip/hip_runtime.h>

#define HIDDEN   2048
#define T_STEPS  8192
#define WASHOUT  200
#define NWG      32
#define NTHR     1024
#define ROWS_PER_WG   (HIDDEN / NWG)       // 64
#define ROWS_PER_WAVE (ROWS_PER_WG / 16)   // 4 rows per wave
#define COLS     32                        // columns per lane (2048/64)

// ws layout: unsigned long long buf[2][HIDDEN] -- {value:hi32, step:lo32} pairs.
// 0xAA poison gives step field 0xAAAAAAAA which never matches a real step, so
// no init kernel is needed; exact-match polling self-initializes.

__global__ __launch_bounds__(NTHR, 1) void esn_main(
    const float* __restrict__ u,
    const float* __restrict__ w_in,
    const float* __restrict__ w_res,
    const float* __restrict__ w_out,
    float* __restrict__ out,
    unsigned long long* __restrict__ buf)
{
  const int g  = blockIdx.x;   // 0..31, one WG per CU (co-resident: grid << 256)
  const int j  = threadIdx.x;  // 0..1023
  const int wv = j >> 6;       // wave 0..15
  const int l  = j & 63;       // lane

  __shared__ float x_s[HIDDEN];
  __shared__ float red[16];

  // wave wv of WG g owns rows r0..r0+3; lane l owns cols l+64m
  const int r0 = g * ROWS_PER_WG + wv * ROWS_PER_WAVE;

  float wr[ROWS_PER_WAVE][COLS];
#pragma unroll
  for (int i = 0; i < ROWS_PER_WAVE; ++i)
#pragma unroll
    for (int m = 0; m < COLS; ++m)
      wr[i][m] = w_res[(r0 + i) * HIDDEN + l + 64 * m];

  float win[ROWS_PER_WAVE];
#pragma unroll
  for (int i = 0; i < ROWS_PER_WAVE; ++i) win[i] = w_in[r0 + i];

  const float wo0 = w_out[j];
  const float wo1 = w_out[j + NTHR];

  for (int t = 0; t < T_STEPS; ++t) {
    // all x_s reads of the previous iteration complete before restaging
    __syncthreads();

    float d0 = 0.f, d1 = 0.f, d2 = 0.f, d3 = 0.f;
    if (t > 0) {
      unsigned long long* bp = buf + (unsigned)((t - 1) & 1) * HIDDEN;
      const unsigned want = (unsigned)(t - 1);
#pragma unroll
      for (int k = 0; k < 2; ++k) {
        const int idx = j + NTHR * k;
        unsigned long long p = __hip_atomic_load(bp + idx, __ATOMIC_RELAXED,
                                                 __HIP_MEMORY_SCOPE_AGENT);
        while ((unsigned)p != want) {
          __builtin_amdgcn_s_sleep(1);
          p = __hip_atomic_load(bp + idx, __ATOMIC_RELAXED,
                                __HIP_MEMORY_SCOPE_AGENT);
        }
        x_s[idx] = __uint_as_float((unsigned)(p >> 32));
      }
      __syncthreads();
#pragma unroll
      for (int m = 0; m < COLS; ++m) {
        const float xv = x_s[l + 64 * m];
        d0 = fmaf(wr[0][m], xv, d0);
        d1 = fmaf(wr[1][m], xv, d1);
        d2 = fmaf(wr[2][m], xv, d2);
        d3 = fmaf(wr[3][m], xv, d3);
      }
    }
    // butterfly: every lane ends with the full row sums
#pragma unroll
    for (int off = 32; off >= 1; off >>= 1) {
      d0 += __shfl_xor(d0, off, 64);
      d1 += __shfl_xor(d1, off, 64);
      d2 += __shfl_xor(d2, off, 64);
      d3 += __shfl_xor(d3, off, 64);
    }
    const float ut = u[t];
    if (l < ROWS_PER_WAVE) {
      const float dsel = (l == 0) ? d0 : (l == 1) ? d1 : (l == 2) ? d2 : d3;
      const float wsel = (l == 0) ? win[0] : (l == 1) ? win[1]
                       : (l == 2) ? win[2] : win[3];
      const float xv = tanhf(fmaf(wsel, ut, dsel));
      const unsigned long long pk =
          ((unsigned long long)__float_as_uint(xv) << 32) | (unsigned)t;
      __hip_atomic_store(buf + (unsigned)(t & 1) * HIDDEN + r0 + l, pk,
                         __ATOMIC_RELAXED, __HIP_MEMORY_SCOPE_AGENT);
    }

    // readout of x[t-1] (currently in x_s), rotating WG, off the critical path
    if (t >= WASHOUT + 1 && g == (t & (NWG - 1))) {
      float p = fmaf(x_s[j], wo0, x_s[j + NTHR] * wo1);
#pragma unroll
      for (int off = 32; off >= 1; off >>= 1) p += __shfl_xor(p, off, 64);
      if (l == 0) red[wv] = p;
      __syncthreads();
      if (j == 0) {
        float s = 0.f;
#pragma unroll
        for (int i = 0; i < 16; ++i) s += red[i];
        out[t - 1 - WASHOUT] = s;
      }
    }
  }

  // epilogue: readout of x[T-1]
  if (g == 0) {
    __syncthreads();
    unsigned long long* bp = buf + (unsigned)((T_STEPS - 1) & 1) * HIDDEN;
    const unsigned want = (unsigned)(T_STEPS - 1);
#pragma unroll
    for (int k = 0; k < 2; ++k) {
      const int idx = j + NTHR * k;
      unsigned long long p = __hip_atomic_load(bp + idx, __ATOMIC_RELAXED,
                                               __HIP_MEMORY_SCOPE_AGENT);
      while ((unsigned)p != want) {
        __builtin_amdgcn_s_sleep(1);
        p = __hip_atomic_load(bp + idx, __ATOMIC_RELAXED,
                              __HIP_MEMORY_SCOPE_AGENT);
      }
      x_s[idx] = __uint_as_float((unsigned)(p >> 32));
    }
    __syncthreads();
    float p = fmaf(x_s[j], wo0, x_s[j + NTHR] * wo1);
#pragma unroll
    for (int off = 32; off >= 1; off >>= 1) p += __shfl_xor(p, off, 64);
    if (l == 0) red[wv] = p;
    __syncthreads();
    if (j == 0) {
      float s = 0.f;
#pragma unroll
      for (int i = 0; i < 16; ++i) s += red[i];
      out[T_STEPS - 1 - WASHOUT] = s;
    }
  }
}

extern "C" void kernel_launch(void* const* d_in, const int* in_sizes, int n_in,
                              void* d_out, int out_size, void* d_ws, size_t ws_size,
                              hipStream_t stream) {
  const float* u     = (const float*)d_in[0];
  const float* w_in  = (const float*)d_in[1];
  const float* w_res = (const float*)d_in[2];
  const float* w_out = (const float*)d_in[3];
  float* out = (float*)d_out;
  unsigned long long* buf = (unsigned long long*)d_ws;

  esn_main<<<NWG, NTHR, 0, stream>>>(u, w_in, w_res, w_out, out, buf);
}

// Round 3
// 23113.782 us; speedup vs baseline: 4.0879x; 2.3032x over previous
//
#include <hip/hip_runtime.h>

#define HIDDEN   2048
#define T_STEPS  8192
#define WASHOUT  200
#define NWG      64
#define NTHR     512
#define NWAVE    (NTHR / 64)              // 8 waves
#define ROWS_PER_WG   (HIDDEN / NWG)      // 32
#define ROWS_PER_WAVE (ROWS_PER_WG / NWAVE) // 4
#define MB       8                        // float4 col-blocks per lane (32 cols)

// ws layout:
//   float    xbuf[2][HIDDEN]      @ 0        (16 KB) -- plain float payload
//   unsigned flags[2][NWG*16]     @ 16 KB    (8 KB)  -- per-WG step tags, 64B apart
// 0xAA poison: flag reads 0xAAAAAAAA which never equals a step id -> self-init.

__global__ __launch_bounds__(NTHR, 2) void esn_main(
    const float* __restrict__ u,
    const float* __restrict__ w_in,
    const float* __restrict__ w_res,
    const float* __restrict__ w_out,
    float* __restrict__ out,
    float* __restrict__ xbuf,
    unsigned* __restrict__ flags)
{
  const int g  = blockIdx.x;    // 0..63, one WG per CU (VGPR use forces spread)
  const int j  = threadIdx.x;   // 0..511
  const int wv = j >> 6;        // 0..7
  const int l  = j & 63;

  __shared__ float x_s[HIDDEN];     // 8 KB
  __shared__ float u_s[T_STEPS];    // 32 KB
  __shared__ float red[NWAVE];

  // preload u into LDS
#pragma unroll
  for (int k = 0; k < T_STEPS / NTHR; ++k) u_s[j + NTHR * k] = u[j + NTHR * k];

  // wave wv owns rows r0..r0+3; lane l owns cols {mb*256 + 4l .. +3}
  const int r0 = g * ROWS_PER_WG + wv * ROWS_PER_WAVE;

  float4 wr[ROWS_PER_WAVE][MB];
#pragma unroll
  for (int i = 0; i < ROWS_PER_WAVE; ++i)
#pragma unroll
    for (int mb = 0; mb < MB; ++mb)
      wr[i][mb] = *(const float4*)&w_res[(r0 + i) * HIDDEN + mb * 256 + 4 * l];
  // pin weights in VGPRs: opaque identity prevents rematerialized global loads
#pragma unroll
  for (int i = 0; i < ROWS_PER_WAVE; ++i)
#pragma unroll
    for (int mb = 0; mb < MB; ++mb)
      asm volatile("" : "+v"(wr[i][mb].x), "+v"(wr[i][mb].y),
                        "+v"(wr[i][mb].z), "+v"(wr[i][mb].w));

  float win[ROWS_PER_WAVE];
#pragma unroll
  for (int i = 0; i < ROWS_PER_WAVE; ++i) win[i] = w_in[r0 + i];
  const float4 wo = *(const float4*)&w_out[4 * j];

  __syncthreads();  // u_s ready

  for (int t = 0; t < T_STEPS; ++t) {
    float d0 = 0.f, d1 = 0.f, d2 = 0.f, d3 = 0.f;
    if (t > 0) {
      const unsigned want = (unsigned)(t - 1);
      const unsigned sp   = (unsigned)((t - 1) & 1);
      // thread j stages elements [4j, 4j+4) = producer chunk j/8;
      // lanes 0..7 of wave wv poll flags 8*wv .. 8*wv+7 (covers the wave's span)
      if (l < NWAVE) {
        const unsigned* fp = flags + sp * (NWG * 16) + (8 * wv + l) * 16;
        unsigned v = __hip_atomic_load(fp, __ATOMIC_RELAXED, __HIP_MEMORY_SCOPE_AGENT);
        while (v != want)
          v = __hip_atomic_load(fp, __ATOMIC_RELAXED, __HIP_MEMORY_SCOPE_AGENT);
      }
      // wave reconverged: all producers for this wave's span have published
      __atomic_signal_fence(__ATOMIC_ACQUIRE);
      const unsigned long long* bp =
          (const unsigned long long*)(xbuf + sp * HIDDEN);
      unsigned long long p0 = __hip_atomic_load(bp + 2 * j,     __ATOMIC_RELAXED,
                                                __HIP_MEMORY_SCOPE_AGENT);
      unsigned long long p1 = __hip_atomic_load(bp + 2 * j + 1, __ATOMIC_RELAXED,
                                                __HIP_MEMORY_SCOPE_AGENT);
      float4 xv;
      xv.x = __uint_as_float((unsigned)p0);
      xv.y = __uint_as_float((unsigned)(p0 >> 32));
      xv.z = __uint_as_float((unsigned)p1);
      xv.w = __uint_as_float((unsigned)(p1 >> 32));
      ((float4*)x_s)[j] = xv;
      __syncthreads();  // staging complete

      const float4* xs4 = (const float4*)x_s;
#pragma unroll
      for (int mb = 0; mb < MB; ++mb) {
        const float4 x4 = xs4[mb * 64 + l];   // ds_read_b128
        d0 = fmaf(wr[0][mb].x, x4.x, d0); d0 = fmaf(wr[0][mb].y, x4.y, d0);
        d0 = fmaf(wr[0][mb].z, x4.z, d0); d0 = fmaf(wr[0][mb].w, x4.w, d0);
        d1 = fmaf(wr[1][mb].x, x4.x, d1); d1 = fmaf(wr[1][mb].y, x4.y, d1);
        d1 = fmaf(wr[1][mb].z, x4.z, d1); d1 = fmaf(wr[1][mb].w, x4.w, d1);
        d2 = fmaf(wr[2][mb].x, x4.x, d2); d2 = fmaf(wr[2][mb].y, x4.y, d2);
        d2 = fmaf(wr[2][mb].z, x4.z, d2); d2 = fmaf(wr[2][mb].w, x4.w, d2);
        d3 = fmaf(wr[3][mb].x, x4.x, d3); d3 = fmaf(wr[3][mb].y, x4.y, d3);
        d3 = fmaf(wr[3][mb].z, x4.z, d3); d3 = fmaf(wr[3][mb].w, x4.w, d3);
      }
    }
#pragma unroll
    for (int off = 32; off >= 1; off >>= 1) {
      d0 += __shfl_xor(d0, off, 64);
      d1 += __shfl_xor(d1, off, 64);
      d2 += __shfl_xor(d2, off, 64);
      d3 += __shfl_xor(d3, off, 64);
    }
    const float ut = u_s[t];
    if (l < ROWS_PER_WAVE) {
      const float dsel = (l == 0) ? d0 : (l == 1) ? d1 : (l == 2) ? d2 : d3;
      const float wsel = (l == 0) ? win[0] : (l == 1) ? win[1]
                       : (l == 2) ? win[2] : win[3];
      const float xn = tanhf(fmaf(wsel, ut, dsel));
      __hip_atomic_store(xbuf + (t & 1) * HIDDEN + r0 + l, xn,
                         __ATOMIC_RELAXED, __HIP_MEMORY_SCOPE_AGENT);
    }
    __syncthreads();  // all waves' value stores drained (vmcnt(0) before barrier)
    if (j == 0)
      __hip_atomic_store(flags + (t & 1) * (NWG * 16) + g * 16, (unsigned)t,
                         __ATOMIC_RELEASE, __HIP_MEMORY_SCOPE_AGENT);

    // readout of x[t-1] (in x_s), rotating WG, off the global critical path
    if (t >= WASHOUT + 1 && g == (t & (NWG - 1))) {
      const float4 xv = ((const float4*)x_s)[j];
      float p = fmaf(xv.x, wo.x, fmaf(xv.y, wo.y, fmaf(xv.z, wo.z, xv.w * wo.w)));
#pragma unroll
      for (int off = 32; off >= 1; off >>= 1) p += __shfl_xor(p, off, 64);
      if (l == 0) red[wv] = p;
      __syncthreads();  // x_s readout reads done before next-iter staging writes
      if (j == 0) {
        float s = 0.f;
#pragma unroll
        for (int i = 0; i < NWAVE; ++i) s += red[i];
        out[t - 1 - WASHOUT] = s;
      }
    }
  }

  // epilogue: out[T-1-WASHOUT] = x[T-1] . w_out  (WG 0)
  if (g == 0) {
    const unsigned want = (unsigned)(T_STEPS - 1);
    const unsigned sp   = (unsigned)((T_STEPS - 1) & 1);
    if (l < NWAVE) {
      const unsigned* fp = flags + sp * (NWG * 16) + (8 * wv + l) * 16;
      unsigned v = __hip_atomic_load(fp, __ATOMIC_RELAXED, __HIP_MEMORY_SCOPE_AGENT);
      while (v != want)
        v = __hip_atomic_load(fp, __ATOMIC_RELAXED, __HIP_MEMORY_SCOPE_AGENT);
    }
    __atomic_signal_fence(__ATOMIC_ACQUIRE);
    const unsigned long long* bp = (const unsigned long long*)(xbuf + sp * HIDDEN);
    unsigned long long p0 = __hip_atomic_load(bp + 2 * j,     __ATOMIC_RELAXED,
                                              __HIP_MEMORY_SCOPE_AGENT);
    unsigned long long p1 = __hip_atomic_load(bp + 2 * j + 1, __ATOMIC_RELAXED,
                                              __HIP_MEMORY_SCOPE_AGENT);
    float4 xv;
    xv.x = __uint_as_float((unsigned)p0);
    xv.y = __uint_as_float((unsigned)(p0 >> 32));
    xv.z = __uint_as_float((unsigned)p1);
    xv.w = __uint_as_float((unsigned)(p1 >> 32));
    ((float4*)x_s)[j] = xv;
    __syncthreads();
    const float4 x4 = ((const float4*)x_s)[j];
    float p = fmaf(x4.x, wo.x, fmaf(x4.y, wo.y, fmaf(x4.z, wo.z, x4.w * wo.w)));
#pragma unroll
    for (int off = 32; off >= 1; off >>= 1) p += __shfl_xor(p, off, 64);
    if (l == 0) red[wv] = p;
    __syncthreads();
    if (j == 0) {
      float s = 0.f;
#pragma unroll
      for (int i = 0; i < NWAVE; ++i) s += red[i];
      out[T_STEPS - 1 - WASHOUT] = s;
    }
  }
}

extern "C" void kernel_launch(void* const* d_in, const int* in_sizes, int n_in,
                              void* d_out, int out_size, void* d_ws, size_t ws_size,
                              hipStream_t stream) {
  const float* u     = (const float*)d_in[0];
  const float* w_in  = (const float*)d_in[1];
  const float* w_res = (const float*)d_in[2];
  const float* w_out = (const float*)d_in[3];
  float* out      = (float*)d_out;
  float* xbuf     = (float*)d_ws;
  unsigned* flags = (unsigned*)((char*)d_ws + 2 * HIDDEN * sizeof(float));

  esn_main<<<NWG, NTHR, 0, stream>>>(u, w_in, w_res, w_out, out, xbuf, flags);
}